// Round 7
// baseline (1482.994 us; speedup 1.0000x reference)
//
#include <hip/hip_runtime.h>
#include <hip/hip_fp16.h>

#define WG 256

// ---- fp16 helpers: 8 channels <-> uint4 ----
__device__ __forceinline__ void h8_to_f8(uint4 u, float* f) {
    union { unsigned int x; __half2 h; } c;
    c.x = u.x; { float2 v = __half22float2(c.h); f[0] = v.x; f[1] = v.y; }
    c.x = u.y; { float2 v = __half22float2(c.h); f[2] = v.x; f[3] = v.y; }
    c.x = u.z; { float2 v = __half22float2(c.h); f[4] = v.x; f[5] = v.y; }
    c.x = u.w; { float2 v = __half22float2(c.h); f[6] = v.x; f[7] = v.y; }
}
__device__ __forceinline__ uint4 f8_to_h8(const float* f) {
    union { unsigned int x; __half2 h; } a0, a1, a2, a3;
    a0.h = __floats2half2_rn(f[0], f[1]);
    a1.h = __floats2half2_rn(f[2], f[3]);
    a2.h = __floats2half2_rn(f[4], f[5]);
    a3.h = __floats2half2_rn(f[6], f[7]);
    return make_uint4(a0.x, a1.x, a2.x, a3.x);
}
__device__ __forceinline__ uint2 f4_to_h4(float4 v) {
    union { unsigned int x; __half2 h; } a, b;
    a.h = __floats2half2_rn(v.x, v.y);
    b.h = __floats2half2_rn(v.z, v.w);
    return make_uint2(a.x, b.x);
}

// ---------------- setup kernels ----------------

__global__ void k_zero2(int* __restrict__ a, int* __restrict__ b, int n) {
    int i = blockIdx.x * blockDim.x + threadIdx.x;
    if (i < n) { a[i] = 0; b[i] = 0; }
}

__global__ void k_count(const int* __restrict__ dst, int* __restrict__ deg, int E) {
    int e = blockIdx.x * blockDim.x + threadIdx.x;
    if (e < E) atomicAdd(&deg[dst[e]], 1);
}

__global__ void k_dis(const int* __restrict__ deg, float* __restrict__ dis, int N) {
    int n = blockIdx.x * blockDim.x + threadIdx.x;
    if (n < N) {
        int d = deg[n];
        dis[n] = (d > 0) ? rsqrtf((float)d) : 0.0f;
    }
}

// ---- hierarchical scan ----
__global__ __launch_bounds__(1024) void k_scan_blk(const int* __restrict__ deg,
                                                   int* __restrict__ rowptr,
                                                   int* __restrict__ bsum, int N) {
    __shared__ int s[1024];
    int t = threadIdx.x;
    int gid = blockIdx.x * 1024 + t;
    int v = (gid < N) ? deg[gid] : 0;
    s[t] = v;
    __syncthreads();
    for (int off = 1; off < 1024; off <<= 1) {
        int u = (t >= off) ? s[t - off] : 0;
        __syncthreads();
        s[t] += u;
        __syncthreads();
    }
    if (gid < N) rowptr[gid] = s[t] - v;
    if (t == 1023) bsum[blockIdx.x] = s[1023];
}

__global__ void k_scan_top(int* __restrict__ bsum, int* __restrict__ rowptr_last, int nb) {
    if (threadIdx.x == 0 && blockIdx.x == 0) {
        int run = 0;
        for (int i = 0; i < nb; ++i) { int v = bsum[i]; bsum[i] = run; run += v; }
        *rowptr_last = run;
    }
}

__global__ void k_scan_add(int* __restrict__ rowptr, const int* __restrict__ bsum, int N) {
    int gid = blockIdx.x * blockDim.x + threadIdx.x;
    if (gid < N) rowptr[gid] += bsum[gid >> 10];
}

__global__ void k_scatter(const int* __restrict__ src, const int* __restrict__ dst,
                          const int* __restrict__ rowptr, int* __restrict__ fill,
                          const float* __restrict__ dis,
                          int2* __restrict__ emeta, int E) {
    int e = blockIdx.x * blockDim.x + threadIdx.x;
    if (e >= E) return;
    int d = dst[e], s = src[e];
    int slot = rowptr[d] + atomicAdd(&fill[d], 1);
    emeta[slot] = make_int2(s, __float_as_int(dis[s] * dis[d]));
}

// X (B,WIN,N) f32 -> h0 [n][w][b] f32
__global__ void k_xpose(const float* __restrict__ X, float* __restrict__ h0, int N) {
    long long tid = (long long)blockIdx.x * blockDim.x + threadIdx.x;
    if (tid >= (long long)N * 20) return;
    int n = (int)(tid / 20), r = (int)(tid % 20);
    int b = r & 3, w = r >> 2;
    h0[tid] = X[(size_t)(b * 5 + w) * N + n];
}

// ---------------- layer-0 propagation (f32, table L2-resident) ----------------
__global__ void k_spmm20(const int* __restrict__ rowptr, const int2* __restrict__ emeta,
                         const float* __restrict__ hin, float* __restrict__ hout, int N) {
    long long tid = (long long)blockIdx.x * blockDim.x + threadIdx.x;
    if (tid >= (long long)N * 5) return;
    int n = (int)(tid / 5), w = (int)(tid % 5);
    const float4* hin4 = (const float4*)hin;
    float ax = 0.f, ay = 0.f, az = 0.f, aw = 0.f;
    float bx = 0.f, by = 0.f, bz = 0.f, bw = 0.f;
    int j = rowptr[n], j1 = rowptr[n + 1];
    for (; j + 1 < j1; j += 2) {
        int2 m0 = emeta[j], m1 = emeta[j + 1];
        float4 g0 = hin4[(size_t)m0.x * 5 + w];
        float4 g1 = hin4[(size_t)m1.x * 5 + w];
        float w0 = __int_as_float(m0.y), w1 = __int_as_float(m1.y);
        ax += w0 * g0.x; ay += w0 * g0.y; az += w0 * g0.z; aw += w0 * g0.w;
        bx += w1 * g1.x; by += w1 * g1.y; bz += w1 * g1.z; bw += w1 * g1.w;
    }
    if (j < j1) {
        int2 m = emeta[j];
        float4 g = hin4[(size_t)m.x * 5 + w];
        float wt = __int_as_float(m.y);
        ax += wt * g.x; ay += wt * g.y; az += wt * g.z; aw += wt * g.w;
    }
    float4 o; o.x = ax + bx; o.y = ay + by; o.z = az + bz; o.w = aw + bw;
    ((float4*)hout)[(size_t)n * 5 + w] = o;
}

// acc[n][b][o] (+)= sum_w h[n][w][b] * W[w][o]
__global__ void k_mm5(const float* __restrict__ h, const float* __restrict__ W,
                      float* __restrict__ acc, int N, int first) {
    __shared__ float w[5 * 32];
    int t = threadIdx.x;
    if (t < 160) w[t] = W[t];
    __syncthreads();
    long long tid = (long long)blockIdx.x * WG + t;
    int node = (int)(tid >> 7);
    if (node >= N) return;
    int b = ((int)tid >> 5) & 3, o = (int)tid & 31;
    const float* hp = h + (size_t)node * 20 + b;
    float a = first ? 0.0f : acc[tid];
#pragma unroll
    for (int f = 0; f < 5; ++f) a += hp[f * 4] * w[f * 32 + o];
    acc[tid] = a;
}

// layer-0 tail: acc += h20*W0[3]; v=tanh(acc+b0); hout(fp16)=v; acc_out = v*Wnext[k=0]
// 8 nodes per 256-thread block (32 lanes/node) -> grid = (N+7)/8
__global__ __launch_bounds__(256) void k_mm5_final(const float* __restrict__ h20,
                                                   const float* __restrict__ W03,
                                                   const float* __restrict__ bias,
                                                   const float* __restrict__ acc_in,
                                                   uint2* __restrict__ hout,
                                                   const float* __restrict__ Wnext,
                                                   float* __restrict__ acc_out, int N) {
    __shared__ float4 wn4[256];
    __shared__ float4 w03[40];
    __shared__ float  hs[8 * 132];
    int t = threadIdx.x;
    wn4[t] = ((const float4*)Wnext)[t];
    if (t < 40) w03[t] = ((const float4*)W03)[t];
    __syncthreads();
    int nl = t >> 5, lane = t & 31, b = lane >> 3, q = lane & 7;
    int n = blockIdx.x * 8 + nl;
    bool valid = (n < N);
    float4 v4 = make_float4(0.f, 0.f, 0.f, 0.f);
    if (valid) {
        float4 a = ((const float4*)acc_in)[(size_t)n * 32 + lane];
#pragma unroll
        for (int w = 0; w < 5; ++w) {
            float hv = h20[(size_t)n * 20 + w * 4 + b];
            float4 wv = w03[w * 8 + q];
            a.x += hv * wv.x; a.y += hv * wv.y; a.z += hv * wv.z; a.w += hv * wv.w;
        }
        float4 b4 = ((const float4*)bias)[q];
        v4.x = tanhf(a.x + b4.x); v4.y = tanhf(a.y + b4.y);
        v4.z = tanhf(a.z + b4.z); v4.w = tanhf(a.w + b4.w);
        hout[(size_t)n * 32 + lane] = f4_to_h4(v4);
    }
    float* hrow = &hs[nl * 132 + b * 33 + q * 4];
    hrow[0] = v4.x; hrow[1] = v4.y; hrow[2] = v4.z; hrow[3] = v4.w;
    __syncthreads();
    float sx = 0.f, sy = 0.f, sz = 0.f, sw = 0.f;
    const float* hb = &hs[nl * 132 + b * 33];
#pragma unroll
    for (int f = 0; f < 32; ++f) {
        float hv = hb[f];
        float4 wv = wn4[f * 8 + q];
        sx += hv * wv.x; sy += hv * wv.y; sz += hv * wv.z; sw += hv * wv.w;
    }
    if (valid) {
        float4 o; o.x = sx; o.y = sy; o.z = sz; o.w = sw;
        ((float4*)acc_out)[(size_t)n * 32 + lane] = o;
    }
}

// ================= fused hops, 16 lanes/node, uint4 gathers =================
// thread t: node_l = t>>4 (16 nodes/block), l = t&15; b = l>>2, og = l&3
// lane owns channels og*8 .. og*8+7 of batch b.
// hs layout: [nb=4*node_l+b][36] (stride 36 floats: 16B-aligned, <=2-way banks)

#define GATHER_BODY                                                              \
    float a[8] = {0.f,0.f,0.f,0.f,0.f,0.f,0.f,0.f};                             \
    if (valid) {                                                                 \
        int j = rowptr[n], j1 = rowptr[n + 1];                                   \
        for (; j + 3 < j1; j += 4) {                                             \
            int2 m0 = emeta[j], m1 = emeta[j+1], m2 = emeta[j+2], m3 = emeta[j+3];\
            uint4 u0 = hin[(size_t)m0.x * 16 + l];                               \
            uint4 u1 = hin[(size_t)m1.x * 16 + l];                               \
            uint4 u2 = hin[(size_t)m2.x * 16 + l];                               \
            uint4 u3 = hin[(size_t)m3.x * 16 + l];                               \
            float g[8];                                                          \
            float w0 = __int_as_float(m0.y), w1 = __int_as_float(m1.y);          \
            float w2 = __int_as_float(m2.y), w3 = __int_as_float(m3.y);          \
            h8_to_f8(u0, g); _Pragma("unroll") for (int i=0;i<8;++i) a[i] += w0*g[i]; \
            h8_to_f8(u1, g); _Pragma("unroll") for (int i=0;i<8;++i) a[i] += w1*g[i]; \
            h8_to_f8(u2, g); _Pragma("unroll") for (int i=0;i<8;++i) a[i] += w2*g[i]; \
            h8_to_f8(u3, g); _Pragma("unroll") for (int i=0;i<8;++i) a[i] += w3*g[i]; \
        }                                                                        \
        for (; j < j1; ++j) {                                                    \
            int2 m = emeta[j];                                                   \
            uint4 u = hin[(size_t)m.x * 16 + l];                                 \
            float g[8];                                                          \
            float w = __int_as_float(m.y);                                       \
            h8_to_f8(u, g); _Pragma("unroll") for (int i=0;i<8;++i) a[i] += w*g[i];   \
        }                                                                        \
    }

// mid hop: hnext = A*hin (fp16); acc += hnext * Wk
__global__ __launch_bounds__(256, 8) void k_hop_fused(const int* __restrict__ rowptr,
                                                      const int2* __restrict__ emeta,
                                                      const uint4* __restrict__ hin,
                                                      uint4* __restrict__ hnext,
                                                      const float* __restrict__ Wk,
                                                      float* __restrict__ acc, int N) {
    __shared__ float4 ws4[256];
    __shared__ float  hs[64 * 36];

    int t = threadIdx.x;
    ws4[t] = ((const float4*)Wk)[t];

    int node_l = t >> 4, l = t & 15;
    int n = blockIdx.x * 16 + node_l;
    bool valid = (n < N);
    int b = l >> 2, og = l & 3;
    int nb = node_l * 4 + b;

    GATHER_BODY
    if (valid) hnext[(size_t)n * 16 + l] = f8_to_h8(a);

    float* hrow = &hs[nb * 36 + og * 8];
#pragma unroll
    for (int i = 0; i < 8; ++i) hrow[i] = a[i];
    __syncthreads();
    if (!valid) return;

    float s[8] = {0.f,0.f,0.f,0.f,0.f,0.f,0.f,0.f};
    const float* hb = &hs[nb * 36];
#pragma unroll
    for (int f = 0; f < 32; ++f) {
        float hv = hb[f];
        float4 w0 = ws4[f * 8 + og * 2];
        float4 w1 = ws4[f * 8 + og * 2 + 1];
        s[0] += hv * w0.x; s[1] += hv * w0.y; s[2] += hv * w0.z; s[3] += hv * w0.w;
        s[4] += hv * w1.x; s[5] += hv * w1.y; s[6] += hv * w1.z; s[7] += hv * w1.w;
    }
    float4* ap = (float4*)acc + ((size_t)n * 4 + b) * 8 + og * 2;
    float4 c0 = ap[0], c1 = ap[1];
    c0.x += s[0]; c0.y += s[1]; c0.z += s[2]; c0.w += s[3];
    c1.x += s[4]; c1.y += s[5]; c1.z += s[6]; c1.w += s[7];
    ap[0] = c0; ap[1] = c1;
}

// last hop of a layer:
// MODE 1: v=tanh(acc+h'*Wk+b); hout(fp16)=v; acc_out = v*Wnext (next layer k=0)
// MODE 2: v=tanh(acc+h'*Wk+b); out_h(f32)=v; pred = v.Wr + br
template <int MODE>
__global__ __launch_bounds__(256, 8) void k_hop_last(const int* __restrict__ rowptr,
                                                     const int2* __restrict__ emeta,
                                                     const uint4* __restrict__ hin,
                                                     const float* __restrict__ Wk,
                                                     const float* __restrict__ acc_in,
                                                     const float* __restrict__ bias,
                                                     uint4* __restrict__ hout,
                                                     const float* __restrict__ Wnext,
                                                     float* __restrict__ acc_out,
                                                     float* __restrict__ out_h,
                                                     const float* __restrict__ Wr,
                                                     const float* __restrict__ br,
                                                     float* __restrict__ pred, int N) {
    __shared__ float4 ws4[256];
    __shared__ float4 wn4[256];
    __shared__ float  hs[64 * 36];

    int t = threadIdx.x;
    ws4[t] = ((const float4*)Wk)[t];
    if (MODE == 1) wn4[t] = ((const float4*)Wnext)[t];

    int node_l = t >> 4, l = t & 15;
    int n = blockIdx.x * 16 + node_l;
    bool valid = (n < N);
    int b = l >> 2, og = l & 3;
    int nb = node_l * 4 + b;

    GATHER_BODY

    float* hrow = &hs[nb * 36 + og * 8];
#pragma unroll
    for (int i = 0; i < 8; ++i) hrow[i] = a[i];
    __syncthreads();

    float s[8] = {0.f,0.f,0.f,0.f,0.f,0.f,0.f,0.f};
    const float* hb = &hs[nb * 36];
#pragma unroll
    for (int f = 0; f < 32; ++f) {
        float hv = hb[f];
        float4 w0 = ws4[f * 8 + og * 2];
        float4 w1 = ws4[f * 8 + og * 2 + 1];
        s[0] += hv * w0.x; s[1] += hv * w0.y; s[2] += hv * w0.z; s[3] += hv * w0.w;
        s[4] += hv * w1.x; s[5] += hv * w1.y; s[6] += hv * w1.z; s[7] += hv * w1.w;
    }

    float v[8];
    if (valid) {
        const float4* ai = (const float4*)acc_in + ((size_t)n * 4 + b) * 8 + og * 2;
        float4 c0 = ai[0], c1 = ai[1];
        float4 b0 = ((const float4*)bias)[og * 2];
        float4 b1 = ((const float4*)bias)[og * 2 + 1];
        v[0] = tanhf(c0.x + s[0] + b0.x); v[1] = tanhf(c0.y + s[1] + b0.y);
        v[2] = tanhf(c0.z + s[2] + b0.z); v[3] = tanhf(c0.w + s[3] + b0.w);
        v[4] = tanhf(c1.x + s[4] + b1.x); v[5] = tanhf(c1.y + s[5] + b1.y);
        v[6] = tanhf(c1.z + s[6] + b1.z); v[7] = tanhf(c1.w + s[7] + b1.w);
    } else {
#pragma unroll
        for (int i = 0; i < 8; ++i) v[i] = 0.f;
    }

    if (MODE == 1) {
        if (valid) hout[(size_t)n * 16 + l] = f8_to_h8(v);
        __syncthreads();           // all reads of hs (h') complete
#pragma unroll
        for (int i = 0; i < 8; ++i) hrow[i] = v[i];
        __syncthreads();
        float r[8] = {0.f,0.f,0.f,0.f,0.f,0.f,0.f,0.f};
#pragma unroll
        for (int f = 0; f < 32; ++f) {
            float hv = hb[f];
            float4 w0 = wn4[f * 8 + og * 2];
            float4 w1 = wn4[f * 8 + og * 2 + 1];
            r[0] += hv * w0.x; r[1] += hv * w0.y; r[2] += hv * w0.z; r[3] += hv * w0.w;
            r[4] += hv * w1.x; r[5] += hv * w1.y; r[6] += hv * w1.z; r[7] += hv * w1.w;
        }
        if (valid) {
            float4* ao = (float4*)acc_out + ((size_t)n * 4 + b) * 8 + og * 2;
            ao[0] = make_float4(r[0], r[1], r[2], r[3]);
            ao[1] = make_float4(r[4], r[5], r[6], r[7]);
        }
    } else {
        if (valid) {
            float4* oh = (float4*)out_h + ((size_t)b * N + n) * 8 + og * 2;
            oh[0] = make_float4(v[0], v[1], v[2], v[3]);
            oh[1] = make_float4(v[4], v[5], v[6], v[7]);
            float4 wr0 = ((const float4*)Wr)[og * 2];
            float4 wr1 = ((const float4*)Wr)[og * 2 + 1];
            float p = v[0]*wr0.x + v[1]*wr0.y + v[2]*wr0.z + v[3]*wr0.w
                    + v[4]*wr1.x + v[5]*wr1.y + v[6]*wr1.z + v[7]*wr1.w;
            p += __shfl_xor(p, 1);
            p += __shfl_xor(p, 2);
            if (og == 0) pred[(size_t)b * N + n] = p + br[0];
        }
    }
}

// ---------------- driver ----------------

extern "C" void kernel_launch(void* const* d_in, const int* in_sizes, int n_in,
                              void* d_out, int out_size, void* d_ws, size_t ws_size,
                              hipStream_t stream) {
    const float* X  = (const float*)d_in[0];
    const int*   ei = (const int*)d_in[1];
    const float* W0 = (const float*)d_in[2];
    const float* b0 = (const float*)d_in[3];
    const float* W1 = (const float*)d_in[4];
    const float* b1 = (const float*)d_in[5];
    const float* W2 = (const float*)d_in[6];
    const float* b2 = (const float*)d_in[7];
    const float* Wr = (const float*)d_in[8];
    const float* br = (const float*)d_in[9];

    const int N = in_sizes[0] / 20;
    const int E = in_sizes[1] / 2;
    const int* src = ei;
    const int* dst = ei + E;
    const int nscan = (N + 1023) / 1024;

    char* ws = (char*)d_ws;
    size_t off = 0;
    auto take = [&](size_t bytes) -> char* {
        char* p = ws + off;
        off = (off + bytes + 255) & ~(size_t)255;
        return p;
    };
    int*   deg    = (int*)  take((size_t)N * 4);
    int*   fill   = (int*)  take((size_t)N * 4);
    int*   rowptr = (int*)  take(((size_t)N + 1) * 4);
    float* dis    = (float*)take((size_t)N * 4);
    int*   bsum   = (int*)  take((size_t)(nscan + 1) * 4);
    int2*  emeta  = (int2*) take((size_t)E * 8);
    float* acc    = (float*)take((size_t)N * 128 * 4);
    void*  h16a   = (void*) take((size_t)N * 128 * 2);   // fp16 node features
    void*  h16b   = (void*) take((size_t)N * 128 * 2);
    float* h20a   = (float*)take((size_t)N * 20 * 4);    // layer-0 f32 ping-pong
    float* h20b   = (float*)take((size_t)N * 20 * 4);
    if (ws_size < off) return;

    dim3 wg(WG);
    auto nb = [](long long total) { return dim3((unsigned)((total + WG - 1) / WG)); };
    dim3 nb8((unsigned)((N + 7) / 8));    // k_mm5_final: 8 nodes/block
    dim3 nb16((unsigned)((N + 15) / 16)); // hop kernels: 16 nodes/block

    // ---- graph/normalization setup ----
    k_zero2<<<nb(N), wg, 0, stream>>>(deg, fill, N);
    k_count<<<nb(E), wg, 0, stream>>>(dst, deg, E);
    k_dis<<<nb(N), wg, 0, stream>>>(deg, dis, N);
    k_scan_blk<<<dim3(nscan), dim3(1024), 0, stream>>>(deg, rowptr, bsum, N);
    k_scan_top<<<dim3(1), dim3(64), 0, stream>>>(bsum, rowptr + N, nscan);
    k_scan_add<<<nb(N), wg, 0, stream>>>(rowptr, bsum, N);
    k_scatter<<<nb(E), wg, 0, stream>>>(src, dst, rowptr, fill, dis, emeta, E);

    // ---- h0 = X^T -> [n][w][4b] ----
    k_xpose<<<nb((long long)N * 20), wg, 0, stream>>>(X, h20a, N);

    float* out_pred = (float*)d_out;
    float* out_h    = (float*)d_out + (size_t)4 * N;

    // ---- layer 0 (5 -> 32), f32 ----
    k_mm5<<<nb((long long)N * 128), wg, 0, stream>>>(h20a, W0, acc, N, 1);
    k_spmm20<<<nb((long long)N * 5), wg, 0, stream>>>(rowptr, emeta, h20a, h20b, N);
    k_mm5<<<nb((long long)N * 128), wg, 0, stream>>>(h20b, W0 + 160, acc, N, 0);
    k_spmm20<<<nb((long long)N * 5), wg, 0, stream>>>(rowptr, emeta, h20b, h20a, N);
    k_mm5<<<nb((long long)N * 128), wg, 0, stream>>>(h20a, W0 + 320, acc, N, 0);
    k_spmm20<<<nb((long long)N * 5), wg, 0, stream>>>(rowptr, emeta, h20a, h20b, N);
    k_mm5_final<<<nb8, wg, 0, stream>>>(h20b, W0 + 480, b0, acc, (uint2*)h16a, W1, acc, N);

    // ---- layer 1 (32 -> 32), fp16 node storage ----
    k_hop_fused<<<nb16, wg, 0, stream>>>(rowptr, emeta, (const uint4*)h16a, (uint4*)h16b,
                                         W1 + 1024, acc, N);
    k_hop_fused<<<nb16, wg, 0, stream>>>(rowptr, emeta, (const uint4*)h16b, (uint4*)h16a,
                                         W1 + 2048, acc, N);
    k_hop_last<1><<<nb16, wg, 0, stream>>>(rowptr, emeta, (const uint4*)h16a, W1 + 3072,
                                           acc, b1, (uint4*)h16b, W2, acc,
                                           nullptr, nullptr, nullptr, nullptr, N);

    // ---- layer 2 (32 -> 32) ----
    k_hop_fused<<<nb16, wg, 0, stream>>>(rowptr, emeta, (const uint4*)h16b, (uint4*)h16a,
                                         W2 + 1024, acc, N);
    k_hop_fused<<<nb16, wg, 0, stream>>>(rowptr, emeta, (const uint4*)h16a, (uint4*)h16b,
                                         W2 + 2048, acc, N);
    k_hop_last<2><<<nb16, wg, 0, stream>>>(rowptr, emeta, (const uint4*)h16b, W2 + 3072,
                                           acc, b2, nullptr, nullptr, nullptr,
                                           out_h, Wr, br, out_pred, N);
}

// Round 8
// 1185.185 us; speedup vs baseline: 1.2513x; 1.2513x over previous
//
#include <hip/hip_runtime.h>
#include <hip/hip_fp16.h>

#define WG 256

// ---- fp16 helpers: 8 channels <-> uint4 ----
__device__ __forceinline__ void h8_to_f8(uint4 u, float* f) {
    union { unsigned int x; __half2 h; } c;
    c.x = u.x; { float2 v = __half22float2(c.h); f[0] = v.x; f[1] = v.y; }
    c.x = u.y; { float2 v = __half22float2(c.h); f[2] = v.x; f[3] = v.y; }
    c.x = u.z; { float2 v = __half22float2(c.h); f[4] = v.x; f[5] = v.y; }
    c.x = u.w; { float2 v = __half22float2(c.h); f[6] = v.x; f[7] = v.y; }
}
__device__ __forceinline__ uint4 f8_to_h8(const float* f) {
    union { unsigned int x; __half2 h; } a0, a1, a2, a3;
    a0.h = __floats2half2_rn(f[0], f[1]);
    a1.h = __floats2half2_rn(f[2], f[3]);
    a2.h = __floats2half2_rn(f[4], f[5]);
    a3.h = __floats2half2_rn(f[6], f[7]);
    return make_uint4(a0.x, a1.x, a2.x, a3.x);
}
__device__ __forceinline__ uint2 f4_to_h4(float4 v) {
    union { unsigned int x; __half2 h; } a, b;
    a.h = __floats2half2_rn(v.x, v.y);
    b.h = __floats2half2_rn(v.z, v.w);
    return make_uint2(a.x, b.x);
}

// ---------------- setup kernels ----------------

__global__ void k_zero2(int* __restrict__ a, int* __restrict__ b, int n) {
    int i = blockIdx.x * blockDim.x + threadIdx.x;
    if (i < n) { a[i] = 0; b[i] = 0; }
}

__global__ void k_count(const int* __restrict__ dst, int* __restrict__ deg, int E) {
    int e = blockIdx.x * blockDim.x + threadIdx.x;
    if (e < E) atomicAdd(&deg[dst[e]], 1);
}

__global__ void k_dis(const int* __restrict__ deg, float* __restrict__ dis, int N) {
    int n = blockIdx.x * blockDim.x + threadIdx.x;
    if (n < N) {
        int d = deg[n];
        dis[n] = (d > 0) ? rsqrtf((float)d) : 0.0f;
    }
}

// ---- hierarchical scan ----
__global__ __launch_bounds__(1024) void k_scan_blk(const int* __restrict__ deg,
                                                   int* __restrict__ rowptr,
                                                   int* __restrict__ bsum, int N) {
    __shared__ int s[1024];
    int t = threadIdx.x;
    int gid = blockIdx.x * 1024 + t;
    int v = (gid < N) ? deg[gid] : 0;
    s[t] = v;
    __syncthreads();
    for (int off = 1; off < 1024; off <<= 1) {
        int u = (t >= off) ? s[t - off] : 0;
        __syncthreads();
        s[t] += u;
        __syncthreads();
    }
    if (gid < N) rowptr[gid] = s[t] - v;
    if (t == 1023) bsum[blockIdx.x] = s[1023];
}

__global__ void k_scan_top(int* __restrict__ bsum, int* __restrict__ rowptr_last, int nb) {
    if (threadIdx.x == 0 && blockIdx.x == 0) {
        int run = 0;
        for (int i = 0; i < nb; ++i) { int v = bsum[i]; bsum[i] = run; run += v; }
        *rowptr_last = run;
    }
}

__global__ void k_scan_add(int* __restrict__ rowptr, const int* __restrict__ bsum, int N) {
    int gid = blockIdx.x * blockDim.x + threadIdx.x;
    if (gid < N) rowptr[gid] += bsum[gid >> 10];
}

__global__ void k_scatter(const int* __restrict__ src, const int* __restrict__ dst,
                          const int* __restrict__ rowptr, int* __restrict__ fill,
                          const float* __restrict__ dis,
                          int2* __restrict__ emeta, int E) {
    int e = blockIdx.x * blockDim.x + threadIdx.x;
    if (e >= E) return;
    int d = dst[e], s = src[e];
    int slot = rowptr[d] + atomicAdd(&fill[d], 1);
    emeta[slot] = make_int2(s, __float_as_int(dis[s] * dis[d]));
}

// X (B,WIN,N) f32 -> h0 [n][w][b] f32
__global__ void k_xpose(const float* __restrict__ X, float* __restrict__ h0, int N) {
    long long tid = (long long)blockIdx.x * blockDim.x + threadIdx.x;
    if (tid >= (long long)N * 20) return;
    int n = (int)(tid / 20), r = (int)(tid % 20);
    int b = r & 3, w = r >> 2;
    h0[tid] = X[(size_t)(b * 5 + w) * N + n];
}

// ---------------- layer-0 propagation (f32, table L2-resident) ----------------
__global__ void k_spmm20(const int* __restrict__ rowptr, const int2* __restrict__ emeta,
                         const float* __restrict__ hin, float* __restrict__ hout, int N) {
    long long tid = (long long)blockIdx.x * blockDim.x + threadIdx.x;
    if (tid >= (long long)N * 5) return;
    int n = (int)(tid / 5), w = (int)(tid % 5);
    const float4* hin4 = (const float4*)hin;
    float ax = 0.f, ay = 0.f, az = 0.f, aw = 0.f;
    float bx = 0.f, by = 0.f, bz = 0.f, bw = 0.f;
    int j = rowptr[n], j1 = rowptr[n + 1];
    for (; j + 1 < j1; j += 2) {
        int2 m0 = emeta[j], m1 = emeta[j + 1];
        float4 g0 = hin4[(size_t)m0.x * 5 + w];
        float4 g1 = hin4[(size_t)m1.x * 5 + w];
        float w0 = __int_as_float(m0.y), w1 = __int_as_float(m1.y);
        ax += w0 * g0.x; ay += w0 * g0.y; az += w0 * g0.z; aw += w0 * g0.w;
        bx += w1 * g1.x; by += w1 * g1.y; bz += w1 * g1.z; bw += w1 * g1.w;
    }
    if (j < j1) {
        int2 m = emeta[j];
        float4 g = hin4[(size_t)m.x * 5 + w];
        float wt = __int_as_float(m.y);
        ax += wt * g.x; ay += wt * g.y; az += wt * g.z; aw += wt * g.w;
    }
    float4 o; o.x = ax + bx; o.y = ay + by; o.z = az + bz; o.w = aw + bw;
    ((float4*)hout)[(size_t)n * 5 + w] = o;
}

// acc[n][b][o] (+)= sum_w h[n][w][b] * W[w][o]
__global__ void k_mm5(const float* __restrict__ h, const float* __restrict__ W,
                      float* __restrict__ acc, int N, int first) {
    __shared__ float w[5 * 32];
    int t = threadIdx.x;
    if (t < 160) w[t] = W[t];
    __syncthreads();
    long long tid = (long long)blockIdx.x * WG + t;
    int node = (int)(tid >> 7);
    if (node >= N) return;
    int b = ((int)tid >> 5) & 3, o = (int)tid & 31;
    const float* hp = h + (size_t)node * 20 + b;
    float a = first ? 0.0f : acc[tid];
#pragma unroll
    for (int f = 0; f < 5; ++f) a += hp[f * 4] * w[f * 32 + o];
    acc[tid] = a;
}

// layer-0 tail: acc += h20*W0[3]; v=tanh(acc+b0); hout(fp16)=v; acc_out = v*Wnext[k=0]
// 8 nodes per 256-thread block (32 lanes/node) -> grid = (N+7)/8
__global__ __launch_bounds__(256) void k_mm5_final(const float* __restrict__ h20,
                                                   const float* __restrict__ W03,
                                                   const float* __restrict__ bias,
                                                   const float* __restrict__ acc_in,
                                                   uint2* __restrict__ hout,
                                                   const float* __restrict__ Wnext,
                                                   float* __restrict__ acc_out, int N) {
    __shared__ float4 wn4[256];
    __shared__ float4 w03[40];
    __shared__ float  hs[8 * 132];
    int t = threadIdx.x;
    wn4[t] = ((const float4*)Wnext)[t];
    if (t < 40) w03[t] = ((const float4*)W03)[t];
    __syncthreads();
    int nl = t >> 5, lane = t & 31, b = lane >> 3, q = lane & 7;
    int n = blockIdx.x * 8 + nl;
    bool valid = (n < N);
    float4 v4 = make_float4(0.f, 0.f, 0.f, 0.f);
    if (valid) {
        float4 a = ((const float4*)acc_in)[(size_t)n * 32 + lane];
#pragma unroll
        for (int w = 0; w < 5; ++w) {
            float hv = h20[(size_t)n * 20 + w * 4 + b];
            float4 wv = w03[w * 8 + q];
            a.x += hv * wv.x; a.y += hv * wv.y; a.z += hv * wv.z; a.w += hv * wv.w;
        }
        float4 b4 = ((const float4*)bias)[q];
        v4.x = tanhf(a.x + b4.x); v4.y = tanhf(a.y + b4.y);
        v4.z = tanhf(a.z + b4.z); v4.w = tanhf(a.w + b4.w);
        hout[(size_t)n * 32 + lane] = f4_to_h4(v4);
    }
    float* hrow = &hs[nl * 132 + b * 33 + q * 4];
    hrow[0] = v4.x; hrow[1] = v4.y; hrow[2] = v4.z; hrow[3] = v4.w;
    __syncthreads();
    float sx = 0.f, sy = 0.f, sz = 0.f, sw = 0.f;
    const float* hb = &hs[nl * 132 + b * 33];
#pragma unroll
    for (int f = 0; f < 32; ++f) {
        float hv = hb[f];
        float4 wv = wn4[f * 8 + q];
        sx += hv * wv.x; sy += hv * wv.y; sz += hv * wv.z; sw += hv * wv.w;
    }
    if (valid) {
        float4 o; o.x = sx; o.y = sy; o.z = sz; o.w = sw;
        ((float4*)acc_out)[(size_t)n * 32 + lane] = o;
    }
}

// ================= fused hops, 16 lanes/node, uint4 gathers =================
// thread t: node_l = t>>4 (16 nodes/block), l = t&15; b = l>>2, og = l&3
// lane owns channels og*8 .. og*8+7 of batch b.
// hs layout: [nb=4*node_l+b][36] (stride 36 floats: 16B-aligned, <=2-way banks)
// __launch_bounds__(256, 4): VGPR cap 128 — (256,8) capped at 64 and SPILLED
// (round 7: FETCH 93->928 MB, 10x regression). ~80-100 live regs needed.

#define GATHER_BODY                                                              \
    float a[8] = {0.f,0.f,0.f,0.f,0.f,0.f,0.f,0.f};                             \
    if (valid) {                                                                 \
        int j = rowptr[n], j1 = rowptr[n + 1];                                   \
        for (; j + 3 < j1; j += 4) {                                             \
            int2 m0 = emeta[j], m1 = emeta[j+1], m2 = emeta[j+2], m3 = emeta[j+3];\
            uint4 u0 = hin[(size_t)m0.x * 16 + l];                               \
            uint4 u1 = hin[(size_t)m1.x * 16 + l];                               \
            uint4 u2 = hin[(size_t)m2.x * 16 + l];                               \
            uint4 u3 = hin[(size_t)m3.x * 16 + l];                               \
            float g[8];                                                          \
            float w0 = __int_as_float(m0.y), w1 = __int_as_float(m1.y);          \
            float w2 = __int_as_float(m2.y), w3 = __int_as_float(m3.y);          \
            h8_to_f8(u0, g); _Pragma("unroll") for (int i=0;i<8;++i) a[i] += w0*g[i]; \
            h8_to_f8(u1, g); _Pragma("unroll") for (int i=0;i<8;++i) a[i] += w1*g[i]; \
            h8_to_f8(u2, g); _Pragma("unroll") for (int i=0;i<8;++i) a[i] += w2*g[i]; \
            h8_to_f8(u3, g); _Pragma("unroll") for (int i=0;i<8;++i) a[i] += w3*g[i]; \
        }                                                                        \
        for (; j < j1; ++j) {                                                    \
            int2 m = emeta[j];                                                   \
            uint4 u = hin[(size_t)m.x * 16 + l];                                 \
            float g[8];                                                          \
            float w = __int_as_float(m.y);                                       \
            h8_to_f8(u, g); _Pragma("unroll") for (int i=0;i<8;++i) a[i] += w*g[i];   \
        }                                                                        \
    }

// mid hop: hnext = A*hin (fp16); acc += hnext * Wk
__global__ __launch_bounds__(256, 4) void k_hop_fused(const int* __restrict__ rowptr,
                                                      const int2* __restrict__ emeta,
                                                      const uint4* __restrict__ hin,
                                                      uint4* __restrict__ hnext,
                                                      const float* __restrict__ Wk,
                                                      float* __restrict__ acc, int N) {
    __shared__ float4 ws4[256];
    __shared__ float  hs[64 * 36];

    int t = threadIdx.x;
    ws4[t] = ((const float4*)Wk)[t];

    int node_l = t >> 4, l = t & 15;
    int n = blockIdx.x * 16 + node_l;
    bool valid = (n < N);
    int b = l >> 2, og = l & 3;
    int nb = node_l * 4 + b;

    GATHER_BODY
    if (valid) hnext[(size_t)n * 16 + l] = f8_to_h8(a);

    float* hrow = &hs[nb * 36 + og * 8];
#pragma unroll
    for (int i = 0; i < 8; ++i) hrow[i] = a[i];
    __syncthreads();
    if (!valid) return;

    float s[8] = {0.f,0.f,0.f,0.f,0.f,0.f,0.f,0.f};
    const float* hb = &hs[nb * 36];
#pragma unroll
    for (int f = 0; f < 32; ++f) {
        float hv = hb[f];
        float4 w0 = ws4[f * 8 + og * 2];
        float4 w1 = ws4[f * 8 + og * 2 + 1];
        s[0] += hv * w0.x; s[1] += hv * w0.y; s[2] += hv * w0.z; s[3] += hv * w0.w;
        s[4] += hv * w1.x; s[5] += hv * w1.y; s[6] += hv * w1.z; s[7] += hv * w1.w;
    }
    float4* ap = (float4*)acc + ((size_t)n * 4 + b) * 8 + og * 2;
    float4 c0 = ap[0], c1 = ap[1];
    c0.x += s[0]; c0.y += s[1]; c0.z += s[2]; c0.w += s[3];
    c1.x += s[4]; c1.y += s[5]; c1.z += s[6]; c1.w += s[7];
    ap[0] = c0; ap[1] = c1;
}

// last hop of a layer:
// MODE 1: v=tanh(acc+h'*Wk+b); hout(fp16)=v; acc_out = v*Wnext (next layer k=0)
// MODE 2: v=tanh(acc+h'*Wk+b); out_h(f32)=v; pred = v.Wr + br
template <int MODE>
__global__ __launch_bounds__(256, 4) void k_hop_last(const int* __restrict__ rowptr,
                                                     const int2* __restrict__ emeta,
                                                     const uint4* __restrict__ hin,
                                                     const float* __restrict__ Wk,
                                                     const float* __restrict__ acc_in,
                                                     const float* __restrict__ bias,
                                                     uint4* __restrict__ hout,
                                                     const float* __restrict__ Wnext,
                                                     float* __restrict__ acc_out,
                                                     float* __restrict__ out_h,
                                                     const float* __restrict__ Wr,
                                                     const float* __restrict__ br,
                                                     float* __restrict__ pred, int N) {
    __shared__ float4 ws4[256];
    __shared__ float4 wn4[256];
    __shared__ float  hs[64 * 36];

    int t = threadIdx.x;
    ws4[t] = ((const float4*)Wk)[t];
    if (MODE == 1) wn4[t] = ((const float4*)Wnext)[t];

    int node_l = t >> 4, l = t & 15;
    int n = blockIdx.x * 16 + node_l;
    bool valid = (n < N);
    int b = l >> 2, og = l & 3;
    int nb = node_l * 4 + b;

    GATHER_BODY

    float* hrow = &hs[nb * 36 + og * 8];
#pragma unroll
    for (int i = 0; i < 8; ++i) hrow[i] = a[i];
    __syncthreads();

    float s[8] = {0.f,0.f,0.f,0.f,0.f,0.f,0.f,0.f};
    const float* hb = &hs[nb * 36];
#pragma unroll
    for (int f = 0; f < 32; ++f) {
        float hv = hb[f];
        float4 w0 = ws4[f * 8 + og * 2];
        float4 w1 = ws4[f * 8 + og * 2 + 1];
        s[0] += hv * w0.x; s[1] += hv * w0.y; s[2] += hv * w0.z; s[3] += hv * w0.w;
        s[4] += hv * w1.x; s[5] += hv * w1.y; s[6] += hv * w1.z; s[7] += hv * w1.w;
    }

    float v[8];
    if (valid) {
        const float4* ai = (const float4*)acc_in + ((size_t)n * 4 + b) * 8 + og * 2;
        float4 c0 = ai[0], c1 = ai[1];
        float4 b0 = ((const float4*)bias)[og * 2];
        float4 b1 = ((const float4*)bias)[og * 2 + 1];
        v[0] = tanhf(c0.x + s[0] + b0.x); v[1] = tanhf(c0.y + s[1] + b0.y);
        v[2] = tanhf(c0.z + s[2] + b0.z); v[3] = tanhf(c0.w + s[3] + b0.w);
        v[4] = tanhf(c1.x + s[4] + b1.x); v[5] = tanhf(c1.y + s[5] + b1.y);
        v[6] = tanhf(c1.z + s[6] + b1.z); v[7] = tanhf(c1.w + s[7] + b1.w);
    } else {
#pragma unroll
        for (int i = 0; i < 8; ++i) v[i] = 0.f;
    }

    if (MODE == 1) {
        if (valid) hout[(size_t)n * 16 + l] = f8_to_h8(v);
        __syncthreads();           // all reads of hs (h') complete
#pragma unroll
        for (int i = 0; i < 8; ++i) hrow[i] = v[i];
        __syncthreads();
        float r[8] = {0.f,0.f,0.f,0.f,0.f,0.f,0.f,0.f};
#pragma unroll
        for (int f = 0; f < 32; ++f) {
            float hv = hb[f];
            float4 w0 = wn4[f * 8 + og * 2];
            float4 w1 = wn4[f * 8 + og * 2 + 1];
            r[0] += hv * w0.x; r[1] += hv * w0.y; r[2] += hv * w0.z; r[3] += hv * w0.w;
            r[4] += hv * w1.x; r[5] += hv * w1.y; r[6] += hv * w1.z; r[7] += hv * w1.w;
        }
        if (valid) {
            float4* ao = (float4*)acc_out + ((size_t)n * 4 + b) * 8 + og * 2;
            ao[0] = make_float4(r[0], r[1], r[2], r[3]);
            ao[1] = make_float4(r[4], r[5], r[6], r[7]);
        }
    } else {
        if (valid) {
            float4* oh = (float4*)out_h + ((size_t)b * N + n) * 8 + og * 2;
            oh[0] = make_float4(v[0], v[1], v[2], v[3]);
            oh[1] = make_float4(v[4], v[5], v[6], v[7]);
            float4 wr0 = ((const float4*)Wr)[og * 2];
            float4 wr1 = ((const float4*)Wr)[og * 2 + 1];
            float p = v[0]*wr0.x + v[1]*wr0.y + v[2]*wr0.z + v[3]*wr0.w
                    + v[4]*wr1.x + v[5]*wr1.y + v[6]*wr1.z + v[7]*wr1.w;
            p += __shfl_xor(p, 1);
            p += __shfl_xor(p, 2);
            if (og == 0) pred[(size_t)b * N + n] = p + br[0];
        }
    }
}

// ---------------- driver ----------------

extern "C" void kernel_launch(void* const* d_in, const int* in_sizes, int n_in,
                              void* d_out, int out_size, void* d_ws, size_t ws_size,
                              hipStream_t stream) {
    const float* X  = (const float*)d_in[0];
    const int*   ei = (const int*)d_in[1];
    const float* W0 = (const float*)d_in[2];
    const float* b0 = (const float*)d_in[3];
    const float* W1 = (const float*)d_in[4];
    const float* b1 = (const float*)d_in[5];
    const float* W2 = (const float*)d_in[6];
    const float* b2 = (const float*)d_in[7];
    const float* Wr = (const float*)d_in[8];
    const float* br = (const float*)d_in[9];

    const int N = in_sizes[0] / 20;
    const int E = in_sizes[1] / 2;
    const int* src = ei;
    const int* dst = ei + E;
    const int nscan = (N + 1023) / 1024;

    char* ws = (char*)d_ws;
    size_t off = 0;
    auto take = [&](size_t bytes) -> char* {
        char* p = ws + off;
        off = (off + bytes + 255) & ~(size_t)255;
        return p;
    };
    int*   deg    = (int*)  take((size_t)N * 4);
    int*   fill   = (int*)  take((size_t)N * 4);
    int*   rowptr = (int*)  take(((size_t)N + 1) * 4);
    float* dis    = (float*)take((size_t)N * 4);
    int*   bsum   = (int*)  take((size_t)(nscan + 1) * 4);
    int2*  emeta  = (int2*) take((size_t)E * 8);
    float* acc    = (float*)take((size_t)N * 128 * 4);
    void*  h16a   = (void*) take((size_t)N * 128 * 2);   // fp16 node features
    void*  h16b   = (void*) take((size_t)N * 128 * 2);
    float* h20a   = (float*)take((size_t)N * 20 * 4);    // layer-0 f32 ping-pong
    float* h20b   = (float*)take((size_t)N * 20 * 4);
    if (ws_size < off) return;

    dim3 wg(WG);
    auto nb = [](long long total) { return dim3((unsigned)((total + WG - 1) / WG)); };
    dim3 nb8((unsigned)((N + 7) / 8));    // k_mm5_final: 8 nodes/block
    dim3 nb16((unsigned)((N + 15) / 16)); // hop kernels: 16 nodes/block

    // ---- graph/normalization setup ----
    k_zero2<<<nb(N), wg, 0, stream>>>(deg, fill, N);
    k_count<<<nb(E), wg, 0, stream>>>(dst, deg, E);
    k_dis<<<nb(N), wg, 0, stream>>>(deg, dis, N);
    k_scan_blk<<<dim3(nscan), dim3(1024), 0, stream>>>(deg, rowptr, bsum, N);
    k_scan_top<<<dim3(1), dim3(64), 0, stream>>>(bsum, rowptr + N, nscan);
    k_scan_add<<<nb(N), wg, 0, stream>>>(rowptr, bsum, N);
    k_scatter<<<nb(E), wg, 0, stream>>>(src, dst, rowptr, fill, dis, emeta, E);

    // ---- h0 = X^T -> [n][w][4b] ----
    k_xpose<<<nb((long long)N * 20), wg, 0, stream>>>(X, h20a, N);

    float* out_pred = (float*)d_out;
    float* out_h    = (float*)d_out + (size_t)4 * N;

    // ---- layer 0 (5 -> 32), f32 ----
    k_mm5<<<nb((long long)N * 128), wg, 0, stream>>>(h20a, W0, acc, N, 1);
    k_spmm20<<<nb((long long)N * 5), wg, 0, stream>>>(rowptr, emeta, h20a, h20b, N);
    k_mm5<<<nb((long long)N * 128), wg, 0, stream>>>(h20b, W0 + 160, acc, N, 0);
    k_spmm20<<<nb((long long)N * 5), wg, 0, stream>>>(rowptr, emeta, h20b, h20a, N);
    k_mm5<<<nb((long long)N * 128), wg, 0, stream>>>(h20a, W0 + 320, acc, N, 0);
    k_spmm20<<<nb((long long)N * 5), wg, 0, stream>>>(rowptr, emeta, h20a, h20b, N);
    k_mm5_final<<<nb8, wg, 0, stream>>>(h20b, W0 + 480, b0, acc, (uint2*)h16a, W1, acc, N);

    // ---- layer 1 (32 -> 32), fp16 node storage ----
    k_hop_fused<<<nb16, wg, 0, stream>>>(rowptr, emeta, (const uint4*)h16a, (uint4*)h16b,
                                         W1 + 1024, acc, N);
    k_hop_fused<<<nb16, wg, 0, stream>>>(rowptr, emeta, (const uint4*)h16b, (uint4*)h16a,
                                         W1 + 2048, acc, N);
    k_hop_last<1><<<nb16, wg, 0, stream>>>(rowptr, emeta, (const uint4*)h16a, W1 + 3072,
                                           acc, b1, (uint4*)h16b, W2, acc,
                                           nullptr, nullptr, nullptr, nullptr, N);

    // ---- layer 2 (32 -> 32) ----
    k_hop_fused<<<nb16, wg, 0, stream>>>(rowptr, emeta, (const uint4*)h16b, (uint4*)h16a,
                                         W2 + 1024, acc, N);
    k_hop_fused<<<nb16, wg, 0, stream>>>(rowptr, emeta, (const uint4*)h16a, (uint4*)h16b,
                                         W2 + 2048, acc, N);
    k_hop_last<2><<<nb16, wg, 0, stream>>>(rowptr, emeta, (const uint4*)h16b, W2 + 3072,
                                           acc, b2, nullptr, nullptr, nullptr,
                                           out_h, Wr, br, out_pred, N);
}

// Round 9
// 594.974 us; speedup vs baseline: 2.4925x; 1.9920x over previous
//
#include <hip/hip_runtime.h>
#include <hip/hip_fp16.h>

#define WG 256

// ---- fp16 helpers: 8 channels <-> uint4 ----
__device__ __forceinline__ void h8_to_f8(uint4 u, float* f) {
    union { unsigned int x; __half2 h; } c;
    c.x = u.x; { float2 v = __half22float2(c.h); f[0] = v.x; f[1] = v.y; }
    c.x = u.y; { float2 v = __half22float2(c.h); f[2] = v.x; f[3] = v.y; }
    c.x = u.z; { float2 v = __half22float2(c.h); f[4] = v.x; f[5] = v.y; }
    c.x = u.w; { float2 v = __half22float2(c.h); f[6] = v.x; f[7] = v.y; }
}
__device__ __forceinline__ uint4 f8_to_h8(const float* f) {
    union { unsigned int x; __half2 h; } a0, a1, a2, a3;
    a0.h = __floats2half2_rn(f[0], f[1]);
    a1.h = __floats2half2_rn(f[2], f[3]);
    a2.h = __floats2half2_rn(f[4], f[5]);
    a3.h = __floats2half2_rn(f[6], f[7]);
    return make_uint4(a0.x, a1.x, a2.x, a3.x);
}
__device__ __forceinline__ uint2 f4_to_h4(float4 v) {
    union { unsigned int x; __half2 h; } a, b;
    a.h = __floats2half2_rn(v.x, v.y);
    b.h = __floats2half2_rn(v.z, v.w);
    return make_uint2(a.x, b.x);
}

// ---------------- setup kernels ----------------

__global__ void k_zero2(int* __restrict__ a, int* __restrict__ b, int n) {
    int i = blockIdx.x * blockDim.x + threadIdx.x;
    if (i < n) { a[i] = 0; b[i] = 0; }
}

__global__ void k_count(const int* __restrict__ dst, int* __restrict__ deg, int E) {
    int e = blockIdx.x * blockDim.x + threadIdx.x;
    if (e < E) atomicAdd(&deg[dst[e]], 1);
}

__global__ void k_dis(const int* __restrict__ deg, float* __restrict__ dis, int N) {
    int n = blockIdx.x * blockDim.x + threadIdx.x;
    if (n < N) {
        int d = deg[n];
        dis[n] = (d > 0) ? rsqrtf((float)d) : 0.0f;
    }
}

// ---- hierarchical scan ----
__global__ __launch_bounds__(1024) void k_scan_blk(const int* __restrict__ deg,
                                                   int* __restrict__ rowptr,
                                                   int* __restrict__ bsum, int N) {
    __shared__ int s[1024];
    int t = threadIdx.x;
    int gid = blockIdx.x * 1024 + t;
    int v = (gid < N) ? deg[gid] : 0;
    s[t] = v;
    __syncthreads();
    for (int off = 1; off < 1024; off <<= 1) {
        int u = (t >= off) ? s[t - off] : 0;
        __syncthreads();
        s[t] += u;
        __syncthreads();
    }
    if (gid < N) rowptr[gid] = s[t] - v;
    if (t == 1023) bsum[blockIdx.x] = s[1023];
}

__global__ void k_scan_top(int* __restrict__ bsum, int* __restrict__ rowptr_last, int nb) {
    if (threadIdx.x == 0 && blockIdx.x == 0) {
        int run = 0;
        for (int i = 0; i < nb; ++i) { int v = bsum[i]; bsum[i] = run; run += v; }
        *rowptr_last = run;
    }
}

__global__ void k_scan_add(int* __restrict__ rowptr, const int* __restrict__ bsum, int N) {
    int gid = blockIdx.x * blockDim.x + threadIdx.x;
    if (gid < N) rowptr[gid] += bsum[gid >> 10];
}

__global__ void k_scatter(const int* __restrict__ src, const int* __restrict__ dst,
                          const int* __restrict__ rowptr, int* __restrict__ fill,
                          const float* __restrict__ dis,
                          int2* __restrict__ emeta, int E) {
    int e = blockIdx.x * blockDim.x + threadIdx.x;
    if (e >= E) return;
    int d = dst[e], s = src[e];
    int slot = rowptr[d] + atomicAdd(&fill[d], 1);
    emeta[slot] = make_int2(s, __float_as_int(dis[s] * dis[d]));
}

// X (B,WIN,N) f32 -> h0 [n][w][b] f32
__global__ void k_xpose(const float* __restrict__ X, float* __restrict__ h0, int N) {
    long long tid = (long long)blockIdx.x * blockDim.x + threadIdx.x;
    if (tid >= (long long)N * 20) return;
    int n = (int)(tid / 20), r = (int)(tid % 20);
    int b = r & 3, w = r >> 2;
    h0[tid] = X[(size_t)(b * 5 + w) * N + n];
}

// ---------------- layer-0 propagation (f32, table L2-resident) ----------------
__global__ void k_spmm20(const int* __restrict__ rowptr, const int2* __restrict__ emeta,
                         const float* __restrict__ hin, float* __restrict__ hout, int N) {
    long long tid = (long long)blockIdx.x * blockDim.x + threadIdx.x;
    if (tid >= (long long)N * 5) return;
    int n = (int)(tid / 5), w = (int)(tid % 5);
    const float4* hin4 = (const float4*)hin;
    float ax = 0.f, ay = 0.f, az = 0.f, aw = 0.f;
    float bx = 0.f, by = 0.f, bz = 0.f, bw = 0.f;
    int j = rowptr[n], j1 = rowptr[n + 1];
    for (; j + 1 < j1; j += 2) {
        int2 m0 = emeta[j], m1 = emeta[j + 1];
        float4 g0 = hin4[(size_t)m0.x * 5 + w];
        float4 g1 = hin4[(size_t)m1.x * 5 + w];
        float w0 = __int_as_float(m0.y), w1 = __int_as_float(m1.y);
        ax += w0 * g0.x; ay += w0 * g0.y; az += w0 * g0.z; aw += w0 * g0.w;
        bx += w1 * g1.x; by += w1 * g1.y; bz += w1 * g1.z; bw += w1 * g1.w;
    }
    if (j < j1) {
        int2 m = emeta[j];
        float4 g = hin4[(size_t)m.x * 5 + w];
        float wt = __int_as_float(m.y);
        ax += wt * g.x; ay += wt * g.y; az += wt * g.z; aw += wt * g.w;
    }
    float4 o; o.x = ax + bx; o.y = ay + by; o.z = az + bz; o.w = aw + bw;
    ((float4*)hout)[(size_t)n * 5 + w] = o;
}

// acc[n][b][o] (+)= sum_w h[n][w][b] * W[w][o]
__global__ void k_mm5(const float* __restrict__ h, const float* __restrict__ W,
                      float* __restrict__ acc, int N, int first) {
    __shared__ float w[5 * 32];
    int t = threadIdx.x;
    if (t < 160) w[t] = W[t];
    __syncthreads();
    long long tid = (long long)blockIdx.x * WG + t;
    int node = (int)(tid >> 7);
    if (node >= N) return;
    int b = ((int)tid >> 5) & 3, o = (int)tid & 31;
    const float* hp = h + (size_t)node * 20 + b;
    float a = first ? 0.0f : acc[tid];
#pragma unroll
    for (int f = 0; f < 5; ++f) a += hp[f * 4] * w[f * 32 + o];
    acc[tid] = a;
}

// layer-0 tail: acc += h20*W0[3]; v=tanh(acc+b0); hout(fp16)=v; acc_out = v*Wnext[k=0]
// 8 nodes per 256-thread block (32 lanes/node) -> grid = (N+7)/8
__global__ __launch_bounds__(256) void k_mm5_final(const float* __restrict__ h20,
                                                   const float* __restrict__ W03,
                                                   const float* __restrict__ bias,
                                                   const float* __restrict__ acc_in,
                                                   uint2* __restrict__ hout,
                                                   const float* __restrict__ Wnext,
                                                   float* __restrict__ acc_out, int N) {
    __shared__ float4 wn4[256];
    __shared__ float4 w03[40];
    __shared__ float  hs[8 * 132];
    int t = threadIdx.x;
    wn4[t] = ((const float4*)Wnext)[t];
    if (t < 40) w03[t] = ((const float4*)W03)[t];
    __syncthreads();
    int nl = t >> 5, lane = t & 31, b = lane >> 3, q = lane & 7;
    int n = blockIdx.x * 8 + nl;
    bool valid = (n < N);
    float4 v4 = make_float4(0.f, 0.f, 0.f, 0.f);
    if (valid) {
        float4 a = ((const float4*)acc_in)[(size_t)n * 32 + lane];
#pragma unroll
        for (int w = 0; w < 5; ++w) {
            float hv = h20[(size_t)n * 20 + w * 4 + b];
            float4 wv = w03[w * 8 + q];
            a.x += hv * wv.x; a.y += hv * wv.y; a.z += hv * wv.z; a.w += hv * wv.w;
        }
        float4 b4 = ((const float4*)bias)[q];
        v4.x = tanhf(a.x + b4.x); v4.y = tanhf(a.y + b4.y);
        v4.z = tanhf(a.z + b4.z); v4.w = tanhf(a.w + b4.w);
        hout[(size_t)n * 32 + lane] = f4_to_h4(v4);
    }
    float* hrow = &hs[nl * 132 + b * 33 + q * 4];
    hrow[0] = v4.x; hrow[1] = v4.y; hrow[2] = v4.z; hrow[3] = v4.w;
    __syncthreads();
    float sx = 0.f, sy = 0.f, sz = 0.f, sw = 0.f;
    const float* hb = &hs[nl * 132 + b * 33];
#pragma unroll
    for (int f = 0; f < 32; ++f) {
        float hv = hb[f];
        float4 wv = wn4[f * 8 + q];
        sx += hv * wv.x; sy += hv * wv.y; sz += hv * wv.z; sw += hv * wv.w;
    }
    if (valid) {
        float4 o; o.x = sx; o.y = sy; o.z = sz; o.w = sw;
        ((float4*)acc_out)[(size_t)n * 32 + lane] = o;
    }
}

// ================= fused hops, 16 lanes/node, uint4 gathers =================
// thread t: node_l = t>>4 (16 nodes/block), l = t&15; b = l>>2, og = l&3
// lane owns channels og*8 .. og*8+7 of batch b.
// hs layout: [nb=4*node_l+b][36] (stride 36 floats: 16B-aligned, <=2-way banks)
// PLAIN __launch_bounds__(256): the min-waves arg maps to a ~256/waves VGPR
// cap on this hipcc ((256,8)->32 VGPR, (256,4)->64 VGPR) and SPILLED both
// times (rounds 7-8: FETCH 93->589+ MB). Round 5's plain (256) gave 88 VGPR,
// zero spill. Let the allocator choose.

#define GATHER_BODY                                                              \
    float a[8] = {0.f,0.f,0.f,0.f,0.f,0.f,0.f,0.f};                             \
    if (valid) {                                                                 \
        int j = rowptr[n], j1 = rowptr[n + 1];                                   \
        for (; j + 3 < j1; j += 4) {                                             \
            int2 m0 = emeta[j], m1 = emeta[j+1], m2 = emeta[j+2], m3 = emeta[j+3];\
            uint4 u0 = hin[(size_t)m0.x * 16 + l];                               \
            uint4 u1 = hin[(size_t)m1.x * 16 + l];                               \
            uint4 u2 = hin[(size_t)m2.x * 16 + l];                               \
            uint4 u3 = hin[(size_t)m3.x * 16 + l];                               \
            float g[8];                                                          \
            float w0 = __int_as_float(m0.y), w1 = __int_as_float(m1.y);          \
            float w2 = __int_as_float(m2.y), w3 = __int_as_float(m3.y);          \
            h8_to_f8(u0, g); _Pragma("unroll") for (int i=0;i<8;++i) a[i] += w0*g[i]; \
            h8_to_f8(u1, g); _Pragma("unroll") for (int i=0;i<8;++i) a[i] += w1*g[i]; \
            h8_to_f8(u2, g); _Pragma("unroll") for (int i=0;i<8;++i) a[i] += w2*g[i]; \
            h8_to_f8(u3, g); _Pragma("unroll") for (int i=0;i<8;++i) a[i] += w3*g[i]; \
        }                                                                        \
        for (; j < j1; ++j) {                                                    \
            int2 m = emeta[j];                                                   \
            uint4 u = hin[(size_t)m.x * 16 + l];                                 \
            float g[8];                                                          \
            float w = __int_as_float(m.y);                                       \
            h8_to_f8(u, g); _Pragma("unroll") for (int i=0;i<8;++i) a[i] += w*g[i];   \
        }                                                                        \
    }

// mid hop: hnext = A*hin (fp16); acc += hnext * Wk
__global__ __launch_bounds__(256) void k_hop_fused(const int* __restrict__ rowptr,
                                                   const int2* __restrict__ emeta,
                                                   const uint4* __restrict__ hin,
                                                   uint4* __restrict__ hnext,
                                                   const float* __restrict__ Wk,
                                                   float* __restrict__ acc, int N) {
    __shared__ float4 ws4[256];
    __shared__ float  hs[64 * 36];

    int t = threadIdx.x;
    ws4[t] = ((const float4*)Wk)[t];

    int node_l = t >> 4, l = t & 15;
    int n = blockIdx.x * 16 + node_l;
    bool valid = (n < N);
    int b = l >> 2, og = l & 3;
    int nb = node_l * 4 + b;

    GATHER_BODY
    if (valid) hnext[(size_t)n * 16 + l] = f8_to_h8(a);

    float* hrow = &hs[nb * 36 + og * 8];
#pragma unroll
    for (int i = 0; i < 8; ++i) hrow[i] = a[i];
    __syncthreads();
    if (!valid) return;

    float s[8] = {0.f,0.f,0.f,0.f,0.f,0.f,0.f,0.f};
    const float* hb = &hs[nb * 36];
#pragma unroll
    for (int f = 0; f < 32; ++f) {
        float hv = hb[f];
        float4 w0 = ws4[f * 8 + og * 2];
        float4 w1 = ws4[f * 8 + og * 2 + 1];
        s[0] += hv * w0.x; s[1] += hv * w0.y; s[2] += hv * w0.z; s[3] += hv * w0.w;
        s[4] += hv * w1.x; s[5] += hv * w1.y; s[6] += hv * w1.z; s[7] += hv * w1.w;
    }
    float4* ap = (float4*)acc + ((size_t)n * 4 + b) * 8 + og * 2;
    float4 c0 = ap[0], c1 = ap[1];
    c0.x += s[0]; c0.y += s[1]; c0.z += s[2]; c0.w += s[3];
    c1.x += s[4]; c1.y += s[5]; c1.z += s[6]; c1.w += s[7];
    ap[0] = c0; ap[1] = c1;
}

// last hop of a layer:
// MODE 1: v=tanh(acc+h'*Wk+b); hout(fp16)=v; acc_out = v*Wnext (next layer k=0)
// MODE 2: v=tanh(acc+h'*Wk+b); out_h(f32)=v; pred = v.Wr + br
template <int MODE>
__global__ __launch_bounds__(256) void k_hop_last(const int* __restrict__ rowptr,
                                                  const int2* __restrict__ emeta,
                                                  const uint4* __restrict__ hin,
                                                  const float* __restrict__ Wk,
                                                  const float* __restrict__ acc_in,
                                                  const float* __restrict__ bias,
                                                  uint4* __restrict__ hout,
                                                  const float* __restrict__ Wnext,
                                                  float* __restrict__ acc_out,
                                                  float* __restrict__ out_h,
                                                  const float* __restrict__ Wr,
                                                  const float* __restrict__ br,
                                                  float* __restrict__ pred, int N) {
    __shared__ float4 ws4[256];
    __shared__ float4 wn4[256];
    __shared__ float  hs[64 * 36];

    int t = threadIdx.x;
    ws4[t] = ((const float4*)Wk)[t];
    if (MODE == 1) wn4[t] = ((const float4*)Wnext)[t];

    int node_l = t >> 4, l = t & 15;
    int n = blockIdx.x * 16 + node_l;
    bool valid = (n < N);
    int b = l >> 2, og = l & 3;
    int nb = node_l * 4 + b;

    GATHER_BODY

    float* hrow = &hs[nb * 36 + og * 8];
#pragma unroll
    for (int i = 0; i < 8; ++i) hrow[i] = a[i];
    __syncthreads();

    float s[8] = {0.f,0.f,0.f,0.f,0.f,0.f,0.f,0.f};
    const float* hb = &hs[nb * 36];
#pragma unroll
    for (int f = 0; f < 32; ++f) {
        float hv = hb[f];
        float4 w0 = ws4[f * 8 + og * 2];
        float4 w1 = ws4[f * 8 + og * 2 + 1];
        s[0] += hv * w0.x; s[1] += hv * w0.y; s[2] += hv * w0.z; s[3] += hv * w0.w;
        s[4] += hv * w1.x; s[5] += hv * w1.y; s[6] += hv * w1.z; s[7] += hv * w1.w;
    }

    float v[8];
    if (valid) {
        const float4* ai = (const float4*)acc_in + ((size_t)n * 4 + b) * 8 + og * 2;
        float4 c0 = ai[0], c1 = ai[1];
        float4 b0 = ((const float4*)bias)[og * 2];
        float4 b1 = ((const float4*)bias)[og * 2 + 1];
        v[0] = tanhf(c0.x + s[0] + b0.x); v[1] = tanhf(c0.y + s[1] + b0.y);
        v[2] = tanhf(c0.z + s[2] + b0.z); v[3] = tanhf(c0.w + s[3] + b0.w);
        v[4] = tanhf(c1.x + s[4] + b1.x); v[5] = tanhf(c1.y + s[5] + b1.y);
        v[6] = tanhf(c1.z + s[6] + b1.z); v[7] = tanhf(c1.w + s[7] + b1.w);
    } else {
#pragma unroll
        for (int i = 0; i < 8; ++i) v[i] = 0.f;
    }

    if (MODE == 1) {
        if (valid) hout[(size_t)n * 16 + l] = f8_to_h8(v);
        __syncthreads();           // all reads of hs (h') complete
#pragma unroll
        for (int i = 0; i < 8; ++i) hrow[i] = v[i];
        __syncthreads();
        float r[8] = {0.f,0.f,0.f,0.f,0.f,0.f,0.f,0.f};
#pragma unroll
        for (int f = 0; f < 32; ++f) {
            float hv = hb[f];
            float4 w0 = wn4[f * 8 + og * 2];
            float4 w1 = wn4[f * 8 + og * 2 + 1];
            r[0] += hv * w0.x; r[1] += hv * w0.y; r[2] += hv * w0.z; r[3] += hv * w0.w;
            r[4] += hv * w1.x; r[5] += hv * w1.y; r[6] += hv * w1.z; r[7] += hv * w1.w;
        }
        if (valid) {
            float4* ao = (float4*)acc_out + ((size_t)n * 4 + b) * 8 + og * 2;
            ao[0] = make_float4(r[0], r[1], r[2], r[3]);
            ao[1] = make_float4(r[4], r[5], r[6], r[7]);
        }
    } else {
        if (valid) {
            float4* oh = (float4*)out_h + ((size_t)b * N + n) * 8 + og * 2;
            oh[0] = make_float4(v[0], v[1], v[2], v[3]);
            oh[1] = make_float4(v[4], v[5], v[6], v[7]);
            float4 wr0 = ((const float4*)Wr)[og * 2];
            float4 wr1 = ((const float4*)Wr)[og * 2 + 1];
            float p = v[0]*wr0.x + v[1]*wr0.y + v[2]*wr0.z + v[3]*wr0.w
                    + v[4]*wr1.x + v[5]*wr1.y + v[6]*wr1.z + v[7]*wr1.w;
            p += __shfl_xor(p, 1);
            p += __shfl_xor(p, 2);
            if (og == 0) pred[(size_t)b * N + n] = p + br[0];
        }
    }
}

// ---------------- driver ----------------

extern "C" void kernel_launch(void* const* d_in, const int* in_sizes, int n_in,
                              void* d_out, int out_size, void* d_ws, size_t ws_size,
                              hipStream_t stream) {
    const float* X  = (const float*)d_in[0];
    const int*   ei = (const int*)d_in[1];
    const float* W0 = (const float*)d_in[2];
    const float* b0 = (const float*)d_in[3];
    const float* W1 = (const float*)d_in[4];
    const float* b1 = (const float*)d_in[5];
    const float* W2 = (const float*)d_in[6];
    const float* b2 = (const float*)d_in[7];
    const float* Wr = (const float*)d_in[8];
    const float* br = (const float*)d_in[9];

    const int N = in_sizes[0] / 20;
    const int E = in_sizes[1] / 2;
    const int* src = ei;
    const int* dst = ei + E;
    const int nscan = (N + 1023) / 1024;

    char* ws = (char*)d_ws;
    size_t off = 0;
    auto take = [&](size_t bytes) -> char* {
        char* p = ws + off;
        off = (off + bytes + 255) & ~(size_t)255;
        return p;
    };
    int*   deg    = (int*)  take((size_t)N * 4);
    int*   fill   = (int*)  take((size_t)N * 4);
    int*   rowptr = (int*)  take(((size_t)N + 1) * 4);
    float* dis    = (float*)take((size_t)N * 4);
    int*   bsum   = (int*)  take((size_t)(nscan + 1) * 4);
    int2*  emeta  = (int2*) take((size_t)E * 8);
    float* acc    = (float*)take((size_t)N * 128 * 4);
    void*  h16a   = (void*) take((size_t)N * 128 * 2);   // fp16 node features
    void*  h16b   = (void*) take((size_t)N * 128 * 2);
    float* h20a   = (float*)take((size_t)N * 20 * 4);    // layer-0 f32 ping-pong
    float* h20b   = (float*)take((size_t)N * 20 * 4);
    if (ws_size < off) return;

    dim3 wg(WG);
    auto nb = [](long long total) { return dim3((unsigned)((total + WG - 1) / WG)); };
    dim3 nb8((unsigned)((N + 7) / 8));    // k_mm5_final: 8 nodes/block
    dim3 nb16((unsigned)((N + 15) / 16)); // hop kernels: 16 nodes/block

    // ---- graph/normalization setup ----
    k_zero2<<<nb(N), wg, 0, stream>>>(deg, fill, N);
    k_count<<<nb(E), wg, 0, stream>>>(dst, deg, E);
    k_dis<<<nb(N), wg, 0, stream>>>(deg, dis, N);
    k_scan_blk<<<dim3(nscan), dim3(1024), 0, stream>>>(deg, rowptr, bsum, N);
    k_scan_top<<<dim3(1), dim3(64), 0, stream>>>(bsum, rowptr + N, nscan);
    k_scan_add<<<nb(N), wg, 0, stream>>>(rowptr, bsum, N);
    k_scatter<<<nb(E), wg, 0, stream>>>(src, dst, rowptr, fill, dis, emeta, E);

    // ---- h0 = X^T -> [n][w][4b] ----
    k_xpose<<<nb((long long)N * 20), wg, 0, stream>>>(X, h20a, N);

    float* out_pred = (float*)d_out;
    float* out_h    = (float*)d_out + (size_t)4 * N;

    // ---- layer 0 (5 -> 32), f32 ----
    k_mm5<<<nb((long long)N * 128), wg, 0, stream>>>(h20a, W0, acc, N, 1);
    k_spmm20<<<nb((long long)N * 5), wg, 0, stream>>>(rowptr, emeta, h20a, h20b, N);
    k_mm5<<<nb((long long)N * 128), wg, 0, stream>>>(h20b, W0 + 160, acc, N, 0);
    k_spmm20<<<nb((long long)N * 5), wg, 0, stream>>>(rowptr, emeta, h20b, h20a, N);
    k_mm5<<<nb((long long)N * 128), wg, 0, stream>>>(h20a, W0 + 320, acc, N, 0);
    k_spmm20<<<nb((long long)N * 5), wg, 0, stream>>>(rowptr, emeta, h20a, h20b, N);
    k_mm5_final<<<nb8, wg, 0, stream>>>(h20b, W0 + 480, b0, acc, (uint2*)h16a, W1, acc, N);

    // ---- layer 1 (32 -> 32), fp16 node storage ----
    k_hop_fused<<<nb16, wg, 0, stream>>>(rowptr, emeta, (const uint4*)h16a, (uint4*)h16b,
                                         W1 + 1024, acc, N);
    k_hop_fused<<<nb16, wg, 0, stream>>>(rowptr, emeta, (const uint4*)h16b, (uint4*)h16a,
                                         W1 + 2048, acc, N);
    k_hop_last<1><<<nb16, wg, 0, stream>>>(rowptr, emeta, (const uint4*)h16a, W1 + 3072,
                                           acc, b1, (uint4*)h16b, W2, acc,
                                           nullptr, nullptr, nullptr, nullptr, N);

    // ---- layer 2 (32 -> 32) ----
    k_hop_fused<<<nb16, wg, 0, stream>>>(rowptr, emeta, (const uint4*)h16b, (uint4*)h16a,
                                         W2 + 1024, acc, N);
    k_hop_fused<<<nb16, wg, 0, stream>>>(rowptr, emeta, (const uint4*)h16a, (uint4*)h16b,
                                         W2 + 2048, acc, N);
    k_hop_last<2><<<nb16, wg, 0, stream>>>(rowptr, emeta, (const uint4*)h16b, W2 + 3072,
                                           acc, b2, nullptr, nullptr, nullptr,
                                           out_h, Wr, br, out_pred, N);
}